// Round 1
// baseline (259.637 us; speedup 1.0000x reference)
//
#include <hip/hip_runtime.h>
#include <math.h>

namespace {
constexpr int B = 8, N = 1024, F = 512, H = 4, D = 128, HD = H * D;
constexpr int ROWS = B * N;  // 8192
constexpr float LEAKY = 0.2f;

// ws layout (floats):
constexpr size_t UV_OFF  = 0;      // [2][H][F]    = 4096 floats
constexpr size_t ATT_OFF = 4096;   // [2][H][ROWS] = 65536 floats
constexpr size_t Y_OFF   = 69632;  // [ROWS][HD]   = 4194304 floats
}

// ---------------- kernel 1: u[h][f] = sum_d W_att[h,f,d] * a_att[h,w,d] ----
extern "C" __global__ void k_uv(const float* __restrict__ Watt,
                                const float* __restrict__ aatt,
                                float* __restrict__ uv) {
    int t = blockIdx.x * 256 + threadIdx.x;  // [2][H][F]
    if (t >= 2 * H * F) return;
    int f = t % F;
    int h = (t / F) % H;
    int w = t / (F * H);
    const float* Wrow = Watt + (size_t)(h * F + f) * D;
    const float* arow = aatt + (size_t)(h * 2 + w) * D;
    float s = 0.f;
#pragma unroll 4
    for (int d = 0; d < D; ++d) s = fmaf(Wrow[d], arow[d], s);
    uv[(size_t)w * (H * F) + h * F + f] = s;
}

// ---------------- kernel 2: att[w][h][row] = X[row,:] . uv[w][h][:] --------
extern "C" __global__ __launch_bounds__(256) void k_att(
    const float* __restrict__ X, const float* __restrict__ uv,
    float* __restrict__ att) {
    int wave = threadIdx.x >> 6, lane = threadIdx.x & 63;
    int row = blockIdx.x * 4 + wave;  // b*N + n
    const float* xr = X + (size_t)row * F;
    float acc0[H] = {}, acc1[H] = {};
    for (int f = lane; f < F; f += 64) {
        float x = xr[f];
#pragma unroll
        for (int h = 0; h < H; ++h) {
            acc0[h] = fmaf(x, uv[h * F + f], acc0[h]);
            acc1[h] = fmaf(x, uv[H * F + h * F + f], acc1[h]);
        }
    }
#pragma unroll
    for (int h = 0; h < H; ++h) {
        float v0 = acc0[h], v1 = acc1[h];
        for (int off = 32; off > 0; off >>= 1) {
            v0 += __shfl_xor(v0, off);
            v1 += __shfl_xor(v1, off);
        }
        if (lane == 0) {
            att[(size_t)h * ROWS + row] = v0;
            att[(size_t)(H + h) * ROWS + row] = v1;
        }
    }
}

// ---------------- kernel 3: Y[row][h*D+d] = sum_f X[row,f] * Wk[h,f,d] -----
// f32 tiled GEMM: C(8192 x 512) = X(8192x512) @ Wk(512 x 512), BN==D so each
// col-block is exactly one head.
extern "C" __global__ __launch_bounds__(256) void k_gemm(
    const float* __restrict__ X, const float* __restrict__ Wk,
    float* __restrict__ Y) {
    constexpr int BM = 128, BN = 128, BK = 16;
    __shared__ float As[BK][132];   // transposed: As[k][r], padded
    __shared__ float Bs[BK][BN];    // Bs[k][c]
    int tid = threadIdx.x;
    int bx = blockIdx.x & 3;        // col block (== head)
    int by = blockIdx.x >> 2;       // row block
    int row0 = by * BM, col0 = bx * BN;
    const float* Wh = Wk + (size_t)bx * F * D;  // [F][D]
    int tx = tid & 15, ty = tid >> 4;
    float acc[8][8] = {};
    for (int k0 = 0; k0 < F; k0 += BK) {
#pragma unroll
        for (int i = 0; i < 2; ++i) {
            int fl = tid + i * 256;          // float4 index, 0..511
            int r = fl >> 2, kq = (fl & 3) * 4;
            float4 v = *reinterpret_cast<const float4*>(
                X + (size_t)(row0 + r) * F + k0 + kq);
            As[kq + 0][r] = v.x;
            As[kq + 1][r] = v.y;
            As[kq + 2][r] = v.z;
            As[kq + 3][r] = v.w;
        }
#pragma unroll
        for (int i = 0; i < 2; ++i) {
            int fl = tid + i * 256;
            int k = fl >> 5, cq = (fl & 31) * 4;
            *reinterpret_cast<float4*>(&Bs[k][cq]) =
                *reinterpret_cast<const float4*>(Wh + (size_t)(k0 + k) * D + cq);
        }
        __syncthreads();
#pragma unroll
        for (int k = 0; k < BK; ++k) {
            float a[8], bb[8];
#pragma unroll
            for (int i = 0; i < 8; ++i) a[i] = As[k][ty * 8 + i];
#pragma unroll
            for (int i = 0; i < 8; ++i) bb[i] = Bs[k][tx * 8 + i];
#pragma unroll
            for (int i = 0; i < 8; ++i)
#pragma unroll
                for (int j = 0; j < 8; ++j)
                    acc[i][j] = fmaf(a[i], bb[j], acc[i][j]);
        }
        __syncthreads();
    }
    int orow = row0 + ty * 8, ocol = col0 + tx * 8;
#pragma unroll
    for (int i = 0; i < 8; ++i)
#pragma unroll
        for (int j = 0; j < 8; j += 4) {
            float4 v = make_float4(acc[i][j], acc[i][j + 1], acc[i][j + 2],
                                   acc[i][j + 3]);
            *reinterpret_cast<float4*>(Y + (size_t)(orow + i) * HD + ocol + j) = v;
        }
}

// ---------------- kernel 4: sparse masked softmax + gather + bias + ELU ----
// one block (256 thr) per (b,i); loop over h inside (A row read once).
extern "C" __global__ __launch_bounds__(256) void k_attn_agg(
    const float* __restrict__ A, const float* __restrict__ att,
    const float* __restrict__ Y, const float* __restrict__ bias,
    float* __restrict__ out) {
    int bi = blockIdx.x;           // b*N + i
    int b = bi >> 10;
    int tid = threadIdx.x;
    __shared__ int idxs[N];
    __shared__ float w[N];
    __shared__ float red[256];
    __shared__ int scan[256];

    // Phase A: load A row (float4), count + exclusive-scan + compact (sorted)
    const float* Arow = A + (size_t)bi * N;
    float4 av = *reinterpret_cast<const float4*>(Arow + tid * 4);
    int cnt = (av.x != 0.f) + (av.y != 0.f) + (av.z != 0.f) + (av.w != 0.f);
    scan[tid] = cnt;
    __syncthreads();
    for (int off = 1; off < 256; off <<= 1) {
        int v = scan[tid];
        int vp = (tid >= off) ? scan[tid - off] : 0;
        __syncthreads();
        scan[tid] = v + vp;
        __syncthreads();
    }
    int nnz = scan[255];
    int wo = scan[tid] - cnt;
    int jb = tid * 4;
    if (av.x != 0.f) idxs[wo++] = jb;
    if (av.y != 0.f) idxs[wo++] = jb + 1;
    if (av.z != 0.f) idxs[wo++] = jb + 2;
    if (av.w != 0.f) idxs[wo++] = jb + 3;
    __syncthreads();

    int d = tid & 127, half = tid >> 7;
    for (int h = 0; h < H; ++h) {
        float sself = att[(size_t)h * ROWS + bi];
        const float* nrow = att + (size_t)(H + h) * ROWS + (bi & ~1023);
        // scores (leaky-relu) + max
        float lmax = -1e30f;
        for (int k = tid; k < nnz; k += 256) {
            float s = sself + nrow[idxs[k]];
            s = s >= 0.f ? s : LEAKY * s;
            w[k] = s;
            lmax = fmaxf(lmax, s);
        }
        red[tid] = lmax;
        __syncthreads();
        for (int st = 128; st > 0; st >>= 1) {
            if (tid < st) red[tid] = fmaxf(red[tid], red[tid + st]);
            __syncthreads();
        }
        float m = red[0];
        __syncthreads();
        // exp + sum
        float lsum = 0.f;
        for (int k = tid; k < nnz; k += 256) {
            float e = __expf(w[k] - m);
            w[k] = e;
            lsum += e;
        }
        red[tid] = lsum;
        __syncthreads();
        for (int st = 128; st > 0; st >>= 1) {
            if (tid < st) red[tid] += red[tid + st];
            __syncthreads();
        }
        float inv = 1.f / red[0];
        __syncthreads();
        // gather-accumulate: two halves of the block cover alternating k
        float acc = 0.f;
        for (int k = half; k < nnz; k += 2) {
            acc += w[k] * Y[(size_t)((b << 10) + idxs[k]) * HD + h * D + d];
        }
        red[tid] = acc;
        __syncthreads();
        if (tid < 128) {
            float v = (red[tid] + red[tid + 128]) * inv + bias[h * D + tid];
            out[(size_t)bi * HD + h * D + tid] = v > 0.f ? v : expm1f(v);
        }
        __syncthreads();
    }
}

extern "C" void kernel_launch(void* const* d_in, const int* in_sizes, int n_in,
                              void* d_out, int out_size, void* d_ws,
                              size_t ws_size, hipStream_t stream) {
    const float* X    = (const float*)d_in[0];
    const float* A    = (const float*)d_in[1];
    const float* Watt = (const float*)d_in[2];
    const float* aatt = (const float*)d_in[3];
    const float* Wk   = (const float*)d_in[4];
    const float* bias = (const float*)d_in[5];
    float* out = (float*)d_out;
    float* ws  = (float*)d_ws;

    float* uv  = ws + UV_OFF;
    float* att = ws + ATT_OFF;
    float* Y   = ws + Y_OFF;

    hipLaunchKernelGGL(k_uv, dim3(16), dim3(256), 0, stream, Watt, aatt, uv);
    hipLaunchKernelGGL(k_att, dim3(ROWS / 4), dim3(256), 0, stream, X, uv, att);
    hipLaunchKernelGGL(k_gemm, dim3((ROWS / 128) * (HD / 128)), dim3(256), 0,
                       stream, X, Wk, Y);
    hipLaunchKernelGGL(k_attn_agg, dim3(ROWS), dim3(256), 0, stream, A, att, Y,
                       bias, out);
}

// Round 2
// 150.253 us; speedup vs baseline: 1.7280x; 1.7280x over previous
//
#include <hip/hip_runtime.h>
#include <math.h>

namespace {
constexpr int B = 8, N = 1024, F = 512, H = 4, D = 128, HD = H * D;
constexpr int ROWS = B * N;  // 8192
constexpr float LEAKY = 0.2f;

// ws layout (floats):
constexpr size_t UV_OFF  = 0;      // [2][H][F]    = 4096 floats
constexpr size_t ATT_OFF = 4096;   // [2][H][ROWS] = 65536 floats
constexpr size_t Y_OFF   = 69632;  // [ROWS][HD]   = 4194304 floats
}

// ---------------- kernel 1: u[h][f] = sum_d W_att[h,f,d] * a_att[h,w,d] ----
extern "C" __global__ void k_uv(const float* __restrict__ Watt,
                                const float* __restrict__ aatt,
                                float* __restrict__ uv) {
    int t = blockIdx.x * 256 + threadIdx.x;  // [2][H][F]
    if (t >= 2 * H * F) return;
    int f = t % F;
    int h = (t / F) % H;
    int w = t / (F * H);
    const float* Wrow = Watt + (size_t)(h * F + f) * D;
    const float* arow = aatt + (size_t)(h * 2 + w) * D;
    float s = 0.f;
#pragma unroll 4
    for (int d = 0; d < D; ++d) s = fmaf(Wrow[d], arow[d], s);
    uv[(size_t)w * (H * F) + h * F + f] = s;
}

// ---------------- kernel 2: att[w][h][row] = X[row,:] . uv[w][h][:] --------
extern "C" __global__ __launch_bounds__(256) void k_att(
    const float* __restrict__ X, const float* __restrict__ uv,
    float* __restrict__ att) {
    int wave = threadIdx.x >> 6, lane = threadIdx.x & 63;
    int row = blockIdx.x * 4 + wave;  // b*N + n
    const float* xr = X + (size_t)row * F;
    float acc0[H] = {}, acc1[H] = {};
    for (int f = lane; f < F; f += 64) {
        float x = xr[f];
#pragma unroll
        for (int h = 0; h < H; ++h) {
            acc0[h] = fmaf(x, uv[h * F + f], acc0[h]);
            acc1[h] = fmaf(x, uv[H * F + h * F + f], acc1[h]);
        }
    }
#pragma unroll
    for (int h = 0; h < H; ++h) {
        float v0 = acc0[h], v1 = acc1[h];
        for (int off = 32; off > 0; off >>= 1) {
            v0 += __shfl_xor(v0, off);
            v1 += __shfl_xor(v1, off);
        }
        if (lane == 0) {
            att[(size_t)h * ROWS + row] = v0;
            att[(size_t)(H + h) * ROWS + row] = v1;
        }
    }
}

// ---------------- kernel 3: Y[row][h*D+d] = sum_f X[row,f] * Wk[h,f,d] -----
extern "C" __global__ __launch_bounds__(256) void k_gemm(
    const float* __restrict__ X, const float* __restrict__ Wk,
    float* __restrict__ Y) {
    constexpr int BM = 128, BN = 128, BK = 16;
    __shared__ float As[BK][132];   // transposed: As[k][r], padded
    __shared__ float Bs[BK][BN];    // Bs[k][c]
    int tid = threadIdx.x;
    int bx = blockIdx.x & 3;        // col block (== head)
    int by = blockIdx.x >> 2;       // row block
    int row0 = by * BM, col0 = bx * BN;
    const float* Wh = Wk + (size_t)bx * F * D;  // [F][D]
    int tx = tid & 15, ty = tid >> 4;
    float acc[8][8] = {};
    for (int k0 = 0; k0 < F; k0 += BK) {
#pragma unroll
        for (int i = 0; i < 2; ++i) {
            int fl = tid + i * 256;          // float4 index, 0..511
            int r = fl >> 2, kq = (fl & 3) * 4;
            float4 v = *reinterpret_cast<const float4*>(
                X + (size_t)(row0 + r) * F + k0 + kq);
            As[kq + 0][r] = v.x;
            As[kq + 1][r] = v.y;
            As[kq + 2][r] = v.z;
            As[kq + 3][r] = v.w;
        }
#pragma unroll
        for (int i = 0; i < 2; ++i) {
            int fl = tid + i * 256;
            int k = fl >> 5, cq = (fl & 31) * 4;
            *reinterpret_cast<float4*>(&Bs[k][cq]) =
                *reinterpret_cast<const float4*>(Wh + (size_t)(k0 + k) * D + cq);
        }
        __syncthreads();
#pragma unroll
        for (int k = 0; k < BK; ++k) {
            float a[8], bb[8];
#pragma unroll
            for (int i = 0; i < 8; ++i) a[i] = As[k][ty * 8 + i];
#pragma unroll
            for (int i = 0; i < 8; ++i) bb[i] = Bs[k][tx * 8 + i];
#pragma unroll
            for (int i = 0; i < 8; ++i)
#pragma unroll
                for (int j = 0; j < 8; ++j)
                    acc[i][j] = fmaf(a[i], bb[j], acc[i][j]);
        }
        __syncthreads();
    }
    int orow = row0 + ty * 8, ocol = col0 + tx * 8;
#pragma unroll
    for (int i = 0; i < 8; ++i)
#pragma unroll
        for (int j = 0; j < 8; j += 4) {
            float4 v = make_float4(acc[i][j], acc[i][j + 1], acc[i][j + 2],
                                   acc[i][j + 3]);
            *reinterpret_cast<float4*>(Y + (size_t)(orow + i) * HD + ocol + j) = v;
        }
}

// ---------------- kernel 4: sparse masked softmax + gather + bias + ELU ----
// one block per (b,i); ONE WAVE PER HEAD. Compaction shared (2 barriers);
// per-head online softmax + gather is barrier-free (wave shuffles only).
extern "C" __global__ __launch_bounds__(256) void k_attn_agg(
    const float* __restrict__ A, const float* __restrict__ att,
    const float* __restrict__ Y, const float* __restrict__ bias,
    float* __restrict__ out) {
    int bi = blockIdx.x;           // b*N + i
    int b = bi >> 10;
    int tid = threadIdx.x;
    int lane = tid & 63, wv = tid >> 6;
    __shared__ int idxs[N];
    __shared__ int wsum[4];

    // Phase A: compact A-row to index list (wave shuffle scan, 2 barriers)
    const float* Arow = A + (size_t)bi * N;
    float4 av = *reinterpret_cast<const float4*>(Arow + tid * 4);
    int cnt = (av.x != 0.f) + (av.y != 0.f) + (av.z != 0.f) + (av.w != 0.f);
    int isc = cnt;  // inclusive scan within wave
#pragma unroll
    for (int off = 1; off < 64; off <<= 1) {
        int t = __shfl_up(isc, off);
        if (lane >= off) isc += t;
    }
    if (lane == 63) wsum[wv] = isc;
    __syncthreads();
    int prefix = 0;
#pragma unroll
    for (int wj = 0; wj < 4; ++wj) prefix += (wj < wv) ? wsum[wj] : 0;
    int nnz = wsum[0] + wsum[1] + wsum[2] + wsum[3];
    int wo = prefix + isc - cnt;
    int jb = tid * 4;
    if (av.x != 0.f) idxs[wo++] = jb;
    if (av.y != 0.f) idxs[wo++] = jb + 1;
    if (av.z != 0.f) idxs[wo++] = jb + 2;
    if (av.w != 0.f) idxs[wo++] = jb + 3;
    __syncthreads();

    // Phase B: wave wv handles head h = wv. Barrier-free.
    int h = wv;
    float sself = att[(size_t)h * ROWS + bi];
    const float* nrow = att + (size_t)(H + h) * ROWS + (size_t)b * N;
    const float* Yb = Y + ((size_t)b * N) * HD + h * D + 2 * lane;
    float m = -1e30f, l = 0.f, ax = 0.f, ay = 0.f;
    for (int c0 = 0; c0 < nnz; c0 += 64) {
        int cn = min(64, nnz - c0);
        int idx = 0;
        float s = -1e30f;
        if (lane < cn) {
            idx = idxs[c0 + lane];
            s = sself + nrow[idx];
            s = s >= 0.f ? s : LEAKY * s;
        }
        float cm = s;
#pragma unroll
        for (int off = 32; off > 0; off >>= 1)
            cm = fmaxf(cm, __shfl_xor(cm, off));
        float mn = fmaxf(m, cm);
        float scale = __expf(m - mn);
        float e = (lane < cn) ? __expf(s - mn) : 0.f;
        float cs = e;
#pragma unroll
        for (int off = 32; off > 0; off >>= 1) cs += __shfl_xor(cs, off);
        l = fmaf(l, scale, cs);
        ax *= scale;
        ay *= scale;
        m = mn;
        int j = 0;
        for (; j + 4 <= cn; j += 4) {
            float w0 = __shfl(e, j), w1 = __shfl(e, j + 1);
            float w2 = __shfl(e, j + 2), w3 = __shfl(e, j + 3);
            int i0 = __shfl(idx, j), i1 = __shfl(idx, j + 1);
            int i2 = __shfl(idx, j + 2), i3 = __shfl(idx, j + 3);
            float2 y0 = *reinterpret_cast<const float2*>(Yb + (size_t)i0 * HD);
            float2 y1 = *reinterpret_cast<const float2*>(Yb + (size_t)i1 * HD);
            float2 y2 = *reinterpret_cast<const float2*>(Yb + (size_t)i2 * HD);
            float2 y3 = *reinterpret_cast<const float2*>(Yb + (size_t)i3 * HD);
            ax = fmaf(w0, y0.x, ax); ay = fmaf(w0, y0.y, ay);
            ax = fmaf(w1, y1.x, ax); ay = fmaf(w1, y1.y, ay);
            ax = fmaf(w2, y2.x, ax); ay = fmaf(w2, y2.y, ay);
            ax = fmaf(w3, y3.x, ax); ay = fmaf(w3, y3.y, ay);
        }
        for (; j < cn; ++j) {
            float wk = __shfl(e, j);
            int ij = __shfl(idx, j);
            float2 yv = *reinterpret_cast<const float2*>(Yb + (size_t)ij * HD);
            ax = fmaf(wk, yv.x, ax);
            ay = fmaf(wk, yv.y, ay);
        }
    }
    float inv = 1.f / l;
    float2 bv = *reinterpret_cast<const float2*>(bias + h * D + 2 * lane);
    float vx = fmaf(ax, inv, 0.f) + bv.x;
    float vy = fmaf(ay, inv, 0.f) + bv.y;
    vx = vx > 0.f ? vx : expm1f(vx);
    vy = vy > 0.f ? vy : expm1f(vy);
    *reinterpret_cast<float2*>(out + (size_t)bi * HD + h * D + 2 * lane) =
        make_float2(vx, vy);
}

extern "C" void kernel_launch(void* const* d_in, const int* in_sizes, int n_in,
                              void* d_out, int out_size, void* d_ws,
                              size_t ws_size, hipStream_t stream) {
    const float* X    = (const float*)d_in[0];
    const float* A    = (const float*)d_in[1];
    const float* Watt = (const float*)d_in[2];
    const float* aatt = (const float*)d_in[3];
    const float* Wk   = (const float*)d_in[4];
    const float* bias = (const float*)d_in[5];
    float* out = (float*)d_out;
    float* ws  = (float*)d_ws;

    float* uv  = ws + UV_OFF;
    float* att = ws + ATT_OFF;
    float* Y   = ws + Y_OFF;

    hipLaunchKernelGGL(k_uv, dim3(16), dim3(256), 0, stream, Watt, aatt, uv);
    hipLaunchKernelGGL(k_att, dim3(ROWS / 4), dim3(256), 0, stream, X, uv, att);
    hipLaunchKernelGGL(k_gemm, dim3((ROWS / 128) * (HD / 128)), dim3(256), 0,
                       stream, X, Wk, Y);
    hipLaunchKernelGGL(k_attn_agg, dim3(ROWS), dim3(256), 0, stream, A, att, Y,
                       bias, out);
}

// Round 3
// 95.603 us; speedup vs baseline: 2.7158x; 1.5716x over previous
//
#include <hip/hip_runtime.h>
#include <hip/hip_bf16.h>
#include <math.h>

namespace {
constexpr int B = 8, N = 1024, F = 512, H = 4, D = 128, HD = H * D;
constexpr int ROWS = B * N;  // 8192
constexpr float LEAKY = 0.2f;

// ws layout (floats):
constexpr size_t UV_OFF  = 0;        // [2][H][F]      = 4096 floats
constexpr size_t ATT_OFF = 4096;     // [2][H][ROWS]   = 65536 floats
constexpr size_t Y_OFF   = 69632;    // [ROWS][HD] f32 = 4194304 floats
constexpr size_t XB_OFF  = 4263936;  // [ROWS][F] bf16 = 2097152 floats
constexpr size_t WKB_OFF = 6361088;  // [HD][F]  bf16  = 131072 floats
}

typedef __attribute__((ext_vector_type(8))) short short8;
typedef __attribute__((ext_vector_type(4))) float f32x4;

// ---------------- kernel 1: u[h][f] = sum_d W_att[h,f,d] * a_att[h,w,d] ----
extern "C" __global__ void k_uv(const float* __restrict__ Watt,
                                const float* __restrict__ aatt,
                                float* __restrict__ uv) {
    int t = blockIdx.x * 256 + threadIdx.x;  // [2][H][F]
    if (t >= 2 * H * F) return;
    int f = t % F;
    int h = (t / F) % H;
    int w = t / (F * H);
    const float* Wrow = Watt + (size_t)(h * F + f) * D;
    const float* arow = aatt + (size_t)(h * 2 + w) * D;
    float s = 0.f;
#pragma unroll 4
    for (int d = 0; d < D; ++d) s = fmaf(Wrow[d], arow[d], s);
    uv[(size_t)w * (H * F) + h * F + f] = s;
}

// ---------------- kernel 1b: Wkb[n][f] = bf16(Wk[h][f][d]), n=h*128+d ------
extern "C" __global__ __launch_bounds__(256) void k_wkb(
    const float* __restrict__ Wk, __hip_bfloat16* __restrict__ Wkb) {
    int n = blockIdx.x;  // 0..511
    int h = n >> 7, d = n & 127;
    const float* src = Wk + (size_t)h * F * D + d;
    for (int f = threadIdx.x; f < F; f += 256)
        Wkb[(size_t)n * F + f] = __float2bfloat16(src[(size_t)f * D]);
}

// ---------------- kernel 2: att scores + X->bf16 conversion ----------------
extern "C" __global__ __launch_bounds__(256) void k_att(
    const float* __restrict__ X, const float* __restrict__ uv,
    float* __restrict__ att, __hip_bfloat16* __restrict__ Xb) {
    int wave = threadIdx.x >> 6, lane = threadIdx.x & 63;
    int row = blockIdx.x * 4 + wave;  // b*N + n
    const float4* xr = reinterpret_cast<const float4*>(X + (size_t)row * F);
    float4 v0 = xr[lane * 2], v1 = xr[lane * 2 + 1];

    union { short8 s; __hip_bfloat16 h[8]; } pk;
    pk.h[0] = __float2bfloat16(v0.x); pk.h[1] = __float2bfloat16(v0.y);
    pk.h[2] = __float2bfloat16(v0.z); pk.h[3] = __float2bfloat16(v0.w);
    pk.h[4] = __float2bfloat16(v1.x); pk.h[5] = __float2bfloat16(v1.y);
    pk.h[6] = __float2bfloat16(v1.z); pk.h[7] = __float2bfloat16(v1.w);
    *reinterpret_cast<short8*>(Xb + (size_t)row * F + lane * 8) = pk.s;

    float acc[2][H];
#pragma unroll
    for (int w = 0; w < 2; ++w)
#pragma unroll
        for (int h = 0; h < H; ++h) {
            const float4* up = reinterpret_cast<const float4*>(
                uv + (size_t)w * (H * F) + h * F + lane * 8);
            float4 u0 = up[0], u1 = up[1];
            float a = 0.f;
            a = fmaf(v0.x, u0.x, a); a = fmaf(v0.y, u0.y, a);
            a = fmaf(v0.z, u0.z, a); a = fmaf(v0.w, u0.w, a);
            a = fmaf(v1.x, u1.x, a); a = fmaf(v1.y, u1.y, a);
            a = fmaf(v1.z, u1.z, a); a = fmaf(v1.w, u1.w, a);
            acc[w][h] = a;
        }
#pragma unroll
    for (int w = 0; w < 2; ++w)
#pragma unroll
        for (int h = 0; h < H; ++h) {
            float v = acc[w][h];
#pragma unroll
            for (int off = 32; off > 0; off >>= 1) v += __shfl_xor(v, off);
            if (lane == 0) att[(size_t)w * (H * ROWS) + h * ROWS + row] = v;
        }
}

// ---------------- kernel 3: MFMA bf16 GEMM  Y = Xb @ Wkb^T -----------------
// Y(8192x512) f32 = Xb(8192x512) bf16 @ B(512x512), B[k][n] = Wkb[n][k].
// 64x64x(BK=64) tiles, 4 waves of 32x32, 16x16x32 MFMA.
// global_load_lds w=16, LDS linear, XOR-swizzled global source (T2/m201).
extern "C" __global__ __launch_bounds__(256) void k_gemm(
    const __hip_bfloat16* __restrict__ Xb,
    const __hip_bfloat16* __restrict__ Wkb, float* __restrict__ Y) {
    __shared__ __align__(16) char smem[16384];  // A: [0,8K) B: [8K,16K)
    int tid = threadIdx.x;
    int lane = tid & 63, wv = tid >> 6;
    int wr = wv >> 1, wc = wv & 1;
    // XCD-aware swizzle: nwg=1024 (%8==0) -> 128 contiguous tiles per XCD
    int lt = (blockIdx.x & 7) * 128 + (blockIdx.x >> 3);
    int bm = lt >> 3, bn = lt & 7;
    int row0 = bm * 64, col0 = bn * 64;

    const ushort* Ag = (const ushort*)Xb;
    const ushort* Bg = (const ushort*)Wkb;

    // LDS read byte-offsets (k0-invariant). row stride = 64*2 = 128B.
    int aoff[2][2], boff[2][2];
#pragma unroll
    for (int ks = 0; ks < 2; ++ks) {
        int cb = ks * 4 + (lane >> 4);  // 16B chunk in K
#pragma unroll
        for (int i = 0; i < 2; ++i) {
            int ra = wr * 32 + i * 16 + (lane & 15);
            aoff[i][ks] = ra * 128 + (cb ^ (ra & 7)) * 16;
            int rb = wc * 32 + i * 16 + (lane & 15);
            boff[i][ks] = 8192 + rb * 128 + (cb ^ (rb & 7)) * 16;
        }
    }
    // staging: round i covers LDS bytes [i*4096 + wv*1024 + lane*16)
    int srow[2], sgb[2];
#pragma unroll
    for (int i = 0; i < 2; ++i) {
        srow[i] = i * 32 + wv * 8 + (lane >> 3);
        sgb[i] = (lane & 7) ^ (srow[i] & 7);  // pre-swizzled source chunk
    }

    f32x4 acc[2][2] = {};
    for (int k0 = 0; k0 < F; k0 += 64) {
        __syncthreads();  // previous tile consumed
#pragma unroll
        for (int i = 0; i < 2; ++i) {
            const ushort* ga = Ag + (size_t)(row0 + srow[i]) * F + k0 + sgb[i] * 8;
            __builtin_amdgcn_global_load_lds(
                (const __attribute__((address_space(1))) uint32_t*)ga,
                (__attribute__((address_space(3))) uint32_t*)(smem + wv * 1024 + i * 4096),
                16, 0, 0);
            const ushort* gb = Bg + (size_t)(col0 + srow[i]) * F + k0 + sgb[i] * 8;
            __builtin_amdgcn_global_load_lds(
                (const __attribute__((address_space(1))) uint32_t*)gb,
                (__attribute__((address_space(3))) uint32_t*)(smem + 8192 + wv * 1024 + i * 4096),
                16, 0, 0);
        }
        __syncthreads();  // compiler drains vmcnt before barrier
#pragma unroll
        for (int ks = 0; ks < 2; ++ks) {
            short8 af[2], bf[2];
#pragma unroll
            for (int i = 0; i < 2; ++i) {
                af[i] = *reinterpret_cast<short8*>(smem + aoff[i][ks]);
                bf[i] = *reinterpret_cast<short8*>(smem + boff[i][ks]);
            }
#pragma unroll
            for (int mi = 0; mi < 2; ++mi)
#pragma unroll
                for (int ni = 0; ni < 2; ++ni)
                    acc[mi][ni] = __builtin_amdgcn_mfma_f32_16x16x32_bf16(
                        af[mi], bf[ni], acc[mi][ni], 0, 0, 0);
        }
    }
    // C/D layout: col = lane&15, row = (lane>>4)*4 + reg
    int cr = (lane >> 4) * 4, cc = lane & 15;
#pragma unroll
    for (int mi = 0; mi < 2; ++mi)
#pragma unroll
        for (int ni = 0; ni < 2; ++ni) {
            int gr = row0 + wr * 32 + mi * 16 + cr;
            int gc = col0 + wc * 32 + ni * 16 + cc;
#pragma unroll
            for (int r = 0; r < 4; ++r)
                Y[(size_t)(gr + r) * HD + gc] = acc[mi][ni][r];
        }
}

// ---------------- kernel 4: sparse masked softmax + gather + bias + ELU ----
extern "C" __global__ __launch_bounds__(256) void k_attn_agg(
    const float* __restrict__ A, const float* __restrict__ att,
    const float* __restrict__ Y, const float* __restrict__ bias,
    float* __restrict__ out) {
    int bi = blockIdx.x;           // b*N + i
    int b = bi >> 10;
    int tid = threadIdx.x;
    int lane = tid & 63, wv = tid >> 6;
    __shared__ int idxs[N];
    __shared__ int wsum[4];

    // Phase A: compact A-row to index list (wave shuffle scan, 2 barriers)
    const float* Arow = A + (size_t)bi * N;
    float4 av = *reinterpret_cast<const float4*>(Arow + tid * 4);
    int cnt = (av.x != 0.f) + (av.y != 0.f) + (av.z != 0.f) + (av.w != 0.f);
    int isc = cnt;
#pragma unroll
    for (int off = 1; off < 64; off <<= 1) {
        int t = __shfl_up(isc, off);
        if (lane >= off) isc += t;
    }
    if (lane == 63) wsum[wv] = isc;
    __syncthreads();
    int prefix = 0;
#pragma unroll
    for (int wj = 0; wj < 4; ++wj) prefix += (wj < wv) ? wsum[wj] : 0;
    int nnz = wsum[0] + wsum[1] + wsum[2] + wsum[3];
    int wo = prefix + isc - cnt;
    int jb = tid * 4;
    if (av.x != 0.f) idxs[wo++] = jb;
    if (av.y != 0.f) idxs[wo++] = jb + 1;
    if (av.z != 0.f) idxs[wo++] = jb + 2;
    if (av.w != 0.f) idxs[wo++] = jb + 3;
    __syncthreads();

    // Phase B: wave wv handles head h = wv. Barrier-free.
    int h = wv;
    float sself = att[(size_t)h * ROWS + bi];
    const float* nrow = att + (size_t)(H + h) * ROWS + (size_t)b * N;
    const float* Yb = Y + ((size_t)b * N) * HD + h * D + 2 * lane;
    float m = -1e30f, l = 0.f, ax = 0.f, ay = 0.f;
    for (int c0 = 0; c0 < nnz; c0 += 64) {
        int cn = min(64, nnz - c0);
        int idx = 0;
        float s = -1e30f;
        if (lane < cn) {
            idx = idxs[c0 + lane];
            s = sself + nrow[idx];
            s = s >= 0.f ? s : LEAKY * s;
        }
        float cm = s;
#pragma unroll
        for (int off = 32; off > 0; off >>= 1)
            cm = fmaxf(cm, __shfl_xor(cm, off));
        float mn = fmaxf(m, cm);
        float scale = __expf(m - mn);
        float e = (lane < cn) ? __expf(s - mn) : 0.f;
        float cs = e;
#pragma unroll
        for (int off = 32; off > 0; off >>= 1) cs += __shfl_xor(cs, off);
        l = fmaf(l, scale, cs);
        ax *= scale;
        ay *= scale;
        m = mn;
        int j = 0;
        for (; j + 4 <= cn; j += 4) {
            float w0 = __shfl(e, j), w1 = __shfl(e, j + 1);
            float w2 = __shfl(e, j + 2), w3 = __shfl(e, j + 3);
            int i0 = __shfl(idx, j), i1 = __shfl(idx, j + 1);
            int i2 = __shfl(idx, j + 2), i3 = __shfl(idx, j + 3);
            float2 y0 = *reinterpret_cast<const float2*>(Yb + (size_t)i0 * HD);
            float2 y1 = *reinterpret_cast<const float2*>(Yb + (size_t)i1 * HD);
            float2 y2 = *reinterpret_cast<const float2*>(Yb + (size_t)i2 * HD);
            float2 y3 = *reinterpret_cast<const float2*>(Yb + (size_t)i3 * HD);
            ax = fmaf(w0, y0.x, ax); ay = fmaf(w0, y0.y, ay);
            ax = fmaf(w1, y1.x, ax); ay = fmaf(w1, y1.y, ay);
            ax = fmaf(w2, y2.x, ax); ay = fmaf(w2, y2.y, ay);
            ax = fmaf(w3, y3.x, ax); ay = fmaf(w3, y3.y, ay);
        }
        for (; j < cn; ++j) {
            float wk = __shfl(e, j);
            int ij = __shfl(idx, j);
            float2 yv = *reinterpret_cast<const float2*>(Yb + (size_t)ij * HD);
            ax = fmaf(wk, yv.x, ax);
            ay = fmaf(wk, yv.y, ay);
        }
    }
    float inv = 1.f / l;
    float2 bv = *reinterpret_cast<const float2*>(bias + h * D + 2 * lane);
    float vx = ax * inv + bv.x;
    float vy = ay * inv + bv.y;
    vx = vx > 0.f ? vx : expm1f(vx);
    vy = vy > 0.f ? vy : expm1f(vy);
    *reinterpret_cast<float2*>(out + (size_t)bi * HD + h * D + 2 * lane) =
        make_float2(vx, vy);
}

extern "C" void kernel_launch(void* const* d_in, const int* in_sizes, int n_in,
                              void* d_out, int out_size, void* d_ws,
                              size_t ws_size, hipStream_t stream) {
    const float* X    = (const float*)d_in[0];
    const float* A    = (const float*)d_in[1];
    const float* Watt = (const float*)d_in[2];
    const float* aatt = (const float*)d_in[3];
    const float* Wk   = (const float*)d_in[4];
    const float* bias = (const float*)d_in[5];
    float* out = (float*)d_out;
    float* ws  = (float*)d_ws;

    float* uv  = ws + UV_OFF;
    float* att = ws + ATT_OFF;
    float* Y   = ws + Y_OFF;
    __hip_bfloat16* Xb  = (__hip_bfloat16*)(ws + XB_OFF);
    __hip_bfloat16* Wkb = (__hip_bfloat16*)(ws + WKB_OFF);

    hipLaunchKernelGGL(k_uv, dim3(16), dim3(256), 0, stream, Watt, aatt, uv);
    hipLaunchKernelGGL(k_wkb, dim3(HD), dim3(256), 0, stream, Wk, Wkb);
    hipLaunchKernelGGL(k_att, dim3(ROWS / 4), dim3(256), 0, stream, X, uv, att, Xb);
    hipLaunchKernelGGL(k_gemm, dim3((ROWS / 64) * (HD / 64)), dim3(256), 0,
                       stream, Xb, Wkb, Y);
    hipLaunchKernelGGL(k_attn_agg, dim3(ROWS), dim3(256), 0, stream, A, att, Y,
                       bias, out);
}

// Round 4
// 85.020 us; speedup vs baseline: 3.0538x; 1.1245x over previous
//
#include <hip/hip_runtime.h>
#include <hip/hip_bf16.h>
#include <math.h>

namespace {
constexpr int B = 8, N = 1024, F = 512, H = 4, D = 128, HD = H * D;
constexpr int ROWS = B * N;  // 8192
constexpr float LEAKY = 0.2f;

// ws layout (float slots):
constexpr size_t UV_OFF  = 0;        // [2][H][F] f32        = 4096
constexpr size_t ATT_OFF = 4096;     // [2][H][ROWS] f32     = 65536
constexpr size_t Y_OFF   = 69632;    // [ROWS][HD] bf16      = 2097152 slots
constexpr size_t XB_OFF  = 2166784;  // [ROWS][F] bf16       = 2097152 slots
constexpr size_t WKB_OFF = 4263936;  // [HD][F] bf16         = 131072 slots
}

typedef __attribute__((ext_vector_type(8))) short short8;
typedef __attribute__((ext_vector_type(4))) float f32x4;

// ---------------- kernel 1: u[h][f] = sum_d W_att[h,f,d] * a_att[h,w,d] ----
extern "C" __global__ void k_uv(const float* __restrict__ Watt,
                                const float* __restrict__ aatt,
                                float* __restrict__ uv) {
    int t = blockIdx.x * 256 + threadIdx.x;  // [2][H][F]
    if (t >= 2 * H * F) return;
    int f = t % F;
    int h = (t / F) % H;
    int w = t / (F * H);
    const float* Wrow = Watt + (size_t)(h * F + f) * D;
    const float* arow = aatt + (size_t)(h * 2 + w) * D;
    float s = 0.f;
#pragma unroll 4
    for (int d = 0; d < D; ++d) s = fmaf(Wrow[d], arow[d], s);
    uv[(size_t)w * (H * F) + h * F + f] = s;
}

// ---------------- kernel 1b: Wkb[n][f] = bf16(Wk[h][f][d]), n=h*128+d ------
extern "C" __global__ __launch_bounds__(256) void k_wkb(
    const float* __restrict__ Wk, __hip_bfloat16* __restrict__ Wkb) {
    int n = blockIdx.x;  // 0..511
    int h = n >> 7, d = n & 127;
    const float* src = Wk + (size_t)h * F * D + d;
    for (int f = threadIdx.x; f < F; f += 256)
        Wkb[(size_t)n * F + f] = __float2bfloat16(src[(size_t)f * D]);
}

// ---------------- kernel 2: att scores + X->bf16 conversion ----------------
extern "C" __global__ __launch_bounds__(256) void k_att(
    const float* __restrict__ X, const float* __restrict__ uv,
    float* __restrict__ att, __hip_bfloat16* __restrict__ Xb) {
    int wave = threadIdx.x >> 6, lane = threadIdx.x & 63;
    int row = blockIdx.x * 4 + wave;  // b*N + n
    const float4* xr = reinterpret_cast<const float4*>(X + (size_t)row * F);
    float4 v0 = xr[lane * 2], v1 = xr[lane * 2 + 1];

    union { short8 s; __hip_bfloat16 h[8]; } pk;
    pk.h[0] = __float2bfloat16(v0.x); pk.h[1] = __float2bfloat16(v0.y);
    pk.h[2] = __float2bfloat16(v0.z); pk.h[3] = __float2bfloat16(v0.w);
    pk.h[4] = __float2bfloat16(v1.x); pk.h[5] = __float2bfloat16(v1.y);
    pk.h[6] = __float2bfloat16(v1.z); pk.h[7] = __float2bfloat16(v1.w);
    *reinterpret_cast<short8*>(Xb + (size_t)row * F + lane * 8) = pk.s;

    float acc[2][H];
#pragma unroll
    for (int w = 0; w < 2; ++w)
#pragma unroll
        for (int h = 0; h < H; ++h) {
            const float4* up = reinterpret_cast<const float4*>(
                uv + (size_t)w * (H * F) + h * F + lane * 8);
            float4 u0 = up[0], u1 = up[1];
            float a = 0.f;
            a = fmaf(v0.x, u0.x, a); a = fmaf(v0.y, u0.y, a);
            a = fmaf(v0.z, u0.z, a); a = fmaf(v0.w, u0.w, a);
            a = fmaf(v1.x, u1.x, a); a = fmaf(v1.y, u1.y, a);
            a = fmaf(v1.z, u1.z, a); a = fmaf(v1.w, u1.w, a);
            acc[w][h] = a;
        }
#pragma unroll
    for (int w = 0; w < 2; ++w)
#pragma unroll
        for (int h = 0; h < H; ++h) {
            float v = acc[w][h];
#pragma unroll
            for (int off = 32; off > 0; off >>= 1) v += __shfl_xor(v, off);
            if (lane == 0) att[(size_t)w * (H * ROWS) + h * ROWS + row] = v;
        }
}

// ---------------- kernel 3: MFMA bf16 GEMM  Y(bf16) = Xb @ Wkb^T -----------
extern "C" __global__ __launch_bounds__(256) void k_gemm(
    const __hip_bfloat16* __restrict__ Xb,
    const __hip_bfloat16* __restrict__ Wkb,
    __hip_bfloat16* __restrict__ Y) {
    __shared__ __align__(16) char smem[16384];  // A: [0,8K) B: [8K,16K)
    int tid = threadIdx.x;
    int lane = tid & 63, wv = tid >> 6;
    int wr = wv >> 1, wc = wv & 1;
    int lt = (blockIdx.x & 7) * 128 + (blockIdx.x >> 3);
    int bm = lt >> 3, bn = lt & 7;
    int row0 = bm * 64, col0 = bn * 64;

    const ushort* Ag = (const ushort*)Xb;
    const ushort* Bg = (const ushort*)Wkb;

    int aoff[2][2], boff[2][2];
#pragma unroll
    for (int ks = 0; ks < 2; ++ks) {
        int cb = ks * 4 + (lane >> 4);  // 16B chunk in K
#pragma unroll
        for (int i = 0; i < 2; ++i) {
            int ra = wr * 32 + i * 16 + (lane & 15);
            aoff[i][ks] = ra * 128 + (cb ^ (ra & 7)) * 16;
            int rb = wc * 32 + i * 16 + (lane & 15);
            boff[i][ks] = 8192 + rb * 128 + (cb ^ (rb & 7)) * 16;
        }
    }
    int srow[2], sgb[2];
#pragma unroll
    for (int i = 0; i < 2; ++i) {
        srow[i] = i * 32 + wv * 8 + (lane >> 3);
        sgb[i] = (lane & 7) ^ (srow[i] & 7);
    }

    f32x4 acc[2][2] = {};
    for (int k0 = 0; k0 < F; k0 += 64) {
        __syncthreads();
#pragma unroll
        for (int i = 0; i < 2; ++i) {
            const ushort* ga = Ag + (size_t)(row0 + srow[i]) * F + k0 + sgb[i] * 8;
            __builtin_amdgcn_global_load_lds(
                (const __attribute__((address_space(1))) uint32_t*)ga,
                (__attribute__((address_space(3))) uint32_t*)(smem + wv * 1024 + i * 4096),
                16, 0, 0);
            const ushort* gb = Bg + (size_t)(col0 + srow[i]) * F + k0 + sgb[i] * 8;
            __builtin_amdgcn_global_load_lds(
                (const __attribute__((address_space(1))) uint32_t*)gb,
                (__attribute__((address_space(3))) uint32_t*)(smem + 8192 + wv * 1024 + i * 4096),
                16, 0, 0);
        }
        __syncthreads();
#pragma unroll
        for (int ks = 0; ks < 2; ++ks) {
            short8 af[2], bf[2];
#pragma unroll
            for (int i = 0; i < 2; ++i) {
                af[i] = *reinterpret_cast<short8*>(smem + aoff[i][ks]);
                bf[i] = *reinterpret_cast<short8*>(smem + boff[i][ks]);
            }
#pragma unroll
            for (int mi = 0; mi < 2; ++mi)
#pragma unroll
                for (int ni = 0; ni < 2; ++ni)
                    acc[mi][ni] = __builtin_amdgcn_mfma_f32_16x16x32_bf16(
                        af[mi], bf[ni], acc[mi][ni], 0, 0, 0);
        }
    }
    int cr = (lane >> 4) * 4, cc = lane & 15;
#pragma unroll
    for (int mi = 0; mi < 2; ++mi)
#pragma unroll
        for (int ni = 0; ni < 2; ++ni) {
            int gr = row0 + wr * 32 + mi * 16 + cr;
            int gc = col0 + wc * 32 + ni * 16 + cc;
#pragma unroll
            for (int r = 0; r < 4; ++r)
                Y[(size_t)(gr + r) * HD + gc] =
                    __float2bfloat16(acc[mi][ni][r]);
        }
}

// ---------------- kernel 4: sparse masked softmax + gather + bias + ELU ----
// one block per (b,i), batch->XCD affinity; one wave per head; Y is bf16.
extern "C" __global__ __launch_bounds__(256) void k_attn_agg(
    const float* __restrict__ A, const float* __restrict__ att,
    const ushort* __restrict__ Y, const float* __restrict__ bias,
    float* __restrict__ out) {
    int g = blockIdx.x;
    int bi = ((g & 7) << 10) | (g >> 3);  // batch (g&7) -> XCD (g&7)
    int b = bi >> 10;
    int tid = threadIdx.x;
    int lane = tid & 63, wv = tid >> 6;
    __shared__ int idxs[N];
    __shared__ int wsum[4];

    // Phase A: compact A-row to index list (wave shuffle scan, 2 barriers)
    const float* Arow = A + (size_t)bi * N;
    float4 av = *reinterpret_cast<const float4*>(Arow + tid * 4);
    int cnt = (av.x != 0.f) + (av.y != 0.f) + (av.z != 0.f) + (av.w != 0.f);
    int isc = cnt;
#pragma unroll
    for (int off = 1; off < 64; off <<= 1) {
        int t = __shfl_up(isc, off);
        if (lane >= off) isc += t;
    }
    if (lane == 63) wsum[wv] = isc;
    __syncthreads();
    int prefix = 0;
#pragma unroll
    for (int wj = 0; wj < 4; ++wj) prefix += (wj < wv) ? wsum[wj] : 0;
    int nnz = wsum[0] + wsum[1] + wsum[2] + wsum[3];
    int wo = prefix + isc - cnt;
    int jb = tid * 4;
    if (av.x != 0.f) idxs[wo++] = jb;
    if (av.y != 0.f) idxs[wo++] = jb + 1;
    if (av.z != 0.f) idxs[wo++] = jb + 2;
    if (av.w != 0.f) idxs[wo++] = jb + 3;
    __syncthreads();

    // Phase B: wave wv handles head h = wv. Barrier-free.
    int h = wv;
    float sself = att[(size_t)h * ROWS + bi];
    const float* nrow = att + (size_t)(H + h) * ROWS + (size_t)b * N;
    const ushort* Yb = Y + ((size_t)b * N) * HD + h * D + 2 * lane;
    float m = -1e30f, l = 0.f, ax = 0.f, ay = 0.f;
    for (int c0 = 0; c0 < nnz; c0 += 64) {
        int cn = min(64, nnz - c0);
        int idx = 0;
        float s = -1e30f;
        if (lane < cn) {
            idx = idxs[c0 + lane];
            s = sself + nrow[idx];
            s = s >= 0.f ? s : LEAKY * s;
        }
        float cm = s;
#pragma unroll
        for (int off = 32; off > 0; off >>= 1)
            cm = fmaxf(cm, __shfl_xor(cm, off));
        float mn = fmaxf(m, cm);
        float scale = __expf(m - mn);
        float e = (lane < cn) ? __expf(s - mn) : 0.f;
        float cs = e;
#pragma unroll
        for (int off = 32; off > 0; off >>= 1) cs += __shfl_xor(cs, off);
        l = fmaf(l, scale, cs);
        ax *= scale;
        ay *= scale;
        m = mn;
        int j = 0;
        for (; j + 8 <= cn; j += 8) {
            float w[8]; int ii[8]; uint yv[8];
#pragma unroll
            for (int q = 0; q < 8; ++q) {
                w[q] = __shfl(e, j + q);
                ii[q] = __shfl(idx, j + q);
            }
#pragma unroll
            for (int q = 0; q < 8; ++q)
                yv[q] = *reinterpret_cast<const uint*>(Yb + (size_t)ii[q] * HD);
#pragma unroll
            for (int q = 0; q < 8; ++q) {
                ax = fmaf(w[q], __uint_as_float(yv[q] << 16), ax);
                ay = fmaf(w[q], __uint_as_float(yv[q] & 0xffff0000u), ay);
            }
        }
        for (; j < cn; ++j) {
            float wk = __shfl(e, j);
            int ij = __shfl(idx, j);
            uint yv = *reinterpret_cast<const uint*>(Yb + (size_t)ij * HD);
            ax = fmaf(wk, __uint_as_float(yv << 16), ax);
            ay = fmaf(wk, __uint_as_float(yv & 0xffff0000u), ay);
        }
    }
    float inv = 1.f / l;
    float2 bv = *reinterpret_cast<const float2*>(bias + h * D + 2 * lane);
    float vx = ax * inv + bv.x;
    float vy = ay * inv + bv.y;
    vx = vx > 0.f ? vx : expm1f(vx);
    vy = vy > 0.f ? vy : expm1f(vy);
    *reinterpret_cast<float2*>(out + (size_t)bi * HD + h * D + 2 * lane) =
        make_float2(vx, vy);
}

extern "C" void kernel_launch(void* const* d_in, const int* in_sizes, int n_in,
                              void* d_out, int out_size, void* d_ws,
                              size_t ws_size, hipStream_t stream) {
    const float* X    = (const float*)d_in[0];
    const float* A    = (const float*)d_in[1];
    const float* Watt = (const float*)d_in[2];
    const float* aatt = (const float*)d_in[3];
    const float* Wk   = (const float*)d_in[4];
    const float* bias = (const float*)d_in[5];
    float* out = (float*)d_out;
    float* ws  = (float*)d_ws;

    float* uv  = ws + UV_OFF;
    float* att = ws + ATT_OFF;
    __hip_bfloat16* Yb  = (__hip_bfloat16*)(ws + Y_OFF);
    __hip_bfloat16* Xb  = (__hip_bfloat16*)(ws + XB_OFF);
    __hip_bfloat16* Wkb = (__hip_bfloat16*)(ws + WKB_OFF);

    hipLaunchKernelGGL(k_uv, dim3(16), dim3(256), 0, stream, Watt, aatt, uv);
    hipLaunchKernelGGL(k_wkb, dim3(HD), dim3(256), 0, stream, Wk, Wkb);
    hipLaunchKernelGGL(k_att, dim3(ROWS / 4), dim3(256), 0, stream, X, uv, att, Xb);
    hipLaunchKernelGGL(k_gemm, dim3((ROWS / 64) * (HD / 64)), dim3(256), 0,
                       stream, Xb, Wkb, Yb);
    hipLaunchKernelGGL(k_attn_agg, dim3(ROWS), dim3(256), 0, stream, A, att,
                       (const ushort*)Yb, bias, out);
}

// Round 6
// 69.644 us; speedup vs baseline: 3.7280x; 1.2208x over previous
//
#include <hip/hip_runtime.h>
#include <hip/hip_bf16.h>
#include <math.h>

namespace {
constexpr int B = 8, N = 1024, F = 512, H = 4, D = 128, HD = H * D;
constexpr int ROWS = B * N;  // 8192
constexpr float LEAKY = 0.2f;

// ws layout (float slots):
constexpr size_t UV_OFF  = 0;        // [2][H][F] f32        = 4096
constexpr size_t ATT_OFF = 4096;     // [2][H][ROWS] f32     = 65536
constexpr size_t Y_OFF   = 69632;    // [ROWS][HD] bf16      = 2097152 slots
constexpr size_t XB_OFF  = 2166784;  // [ROWS][F] bf16       = 2097152 slots
constexpr size_t WKB_OFF = 4263936;  // [HD][F] bf16         = 131072 slots
}

typedef __attribute__((ext_vector_type(8))) short short8;
typedef __attribute__((ext_vector_type(4))) float f32x4;

__device__ __forceinline__ ushort bf16bits(float x) {
    __hip_bfloat16 h = __float2bfloat16(x);
    return *reinterpret_cast<ushort*>(&h);
}
__device__ __forceinline__ float blo(uint u) {
    return __uint_as_float(u << 16);
}
__device__ __forceinline__ float bhi(uint u) {
    return __uint_as_float(u & 0xffff0000u);
}

// ---------------- kernel 1: fused uv + Wkb transpose -----------------------
// blocks 0..15 : Wkb tile transpose (bid = h*4 + ftile)
// blocks 16..31: uv[w][h][f] = sum_d W_att[h,f,d] * a_att[h,w,d]
extern "C" __global__ __launch_bounds__(256) void k_pre(
    const float* __restrict__ Watt, const float* __restrict__ aatt,
    const float* __restrict__ Wk, float* __restrict__ uv,
    __hip_bfloat16* __restrict__ Wkb) {
    __shared__ ushort T[128][136];
    if (blockIdx.x < 16) {
        int h = blockIdx.x >> 2, f0 = (blockIdx.x & 3) * 128;
#pragma unroll
        for (int p = 0; p < 16; ++p) {
            int fi = p * 8 + (threadIdx.x >> 5);
            int d4 = (threadIdx.x & 31) * 4;
            float4 v = *reinterpret_cast<const float4*>(
                Wk + ((size_t)h * F + f0 + fi) * D + d4);
            T[d4 + 0][fi] = bf16bits(v.x);
            T[d4 + 1][fi] = bf16bits(v.y);
            T[d4 + 2][fi] = bf16bits(v.z);
            T[d4 + 3][fi] = bf16bits(v.w);
        }
        __syncthreads();
        // each thread writes one 64-ushort half-row: 8 x uint4 (8 ushorts each)
        int d = threadIdx.x >> 1, hf = threadIdx.x & 1;
        ushort* dst =
            (ushort*)Wkb + (size_t)(h * 128 + d) * F + f0 + hf * 64;
        const ushort* src = &T[d][hf * 64];
#pragma unroll
        for (int q = 0; q < 8; ++q)
            *reinterpret_cast<uint4*>(dst + q * 8) =
                *reinterpret_cast<const uint4*>(src + q * 8);
    } else {
        int t = (blockIdx.x - 16) * 256 + threadIdx.x;  // [2][H][F]
        int f = t % F;
        int h = (t / F) % H;
        int w = t / (F * H);
        const float* Wrow = Watt + (size_t)(h * F + f) * D;
        const float* arow = aatt + (size_t)(h * 2 + w) * D;
        float s = 0.f;
#pragma unroll 4
        for (int d = 0; d < D; ++d) s = fmaf(Wrow[d], arow[d], s);
        uv[(size_t)w * (H * F) + h * F + f] = s;
    }
}

// ---------------- kernel 2: att scores + X->bf16 conversion ----------------
extern "C" __global__ __launch_bounds__(256) void k_att(
    const float* __restrict__ X, const float* __restrict__ uv,
    float* __restrict__ att, __hip_bfloat16* __restrict__ Xb) {
    int wave = threadIdx.x >> 6, lane = threadIdx.x & 63;
    int row = blockIdx.x * 4 + wave;  // b*N + n
    const float4* xr = reinterpret_cast<const float4*>(X + (size_t)row * F);
    float4 v0 = xr[lane * 2], v1 = xr[lane * 2 + 1];

    union { short8 s; __hip_bfloat16 h[8]; } pk;
    pk.h[0] = __float2bfloat16(v0.x); pk.h[1] = __float2bfloat16(v0.y);
    pk.h[2] = __float2bfloat16(v0.z); pk.h[3] = __float2bfloat16(v0.w);
    pk.h[4] = __float2bfloat16(v1.x); pk.h[5] = __float2bfloat16(v1.y);
    pk.h[6] = __float2bfloat16(v1.z); pk.h[7] = __float2bfloat16(v1.w);
    *reinterpret_cast<short8*>(Xb + (size_t)row * F + lane * 8) = pk.s;

    float acc[2][H];
#pragma unroll
    for (int w = 0; w < 2; ++w)
#pragma unroll
        for (int h = 0; h < H; ++h) {
            const float4* up = reinterpret_cast<const float4*>(
                uv + (size_t)w * (H * F) + h * F + lane * 8);
            float4 u0 = up[0], u1 = up[1];
            float a = 0.f;
            a = fmaf(v0.x, u0.x, a); a = fmaf(v0.y, u0.y, a);
            a = fmaf(v0.z, u0.z, a); a = fmaf(v0.w, u0.w, a);
            a = fmaf(v1.x, u1.x, a); a = fmaf(v1.y, u1.y, a);
            a = fmaf(v1.z, u1.z, a); a = fmaf(v1.w, u1.w, a);
            acc[w][h] = a;
        }
#pragma unroll
    for (int w = 0; w < 2; ++w)
#pragma unroll
        for (int h = 0; h < H; ++h) {
            float v = acc[w][h];
#pragma unroll
            for (int off = 32; off > 0; off >>= 1) v += __shfl_xor(v, off);
            if (lane == 0) att[(size_t)w * (H * ROWS) + h * ROWS + row] = v;
        }
}

// ---------------- kernel 3: MFMA bf16 GEMM  Y(bf16) = Xb @ Wkb^T -----------
extern "C" __global__ __launch_bounds__(256) void k_gemm(
    const __hip_bfloat16* __restrict__ Xb,
    const __hip_bfloat16* __restrict__ Wkb,
    __hip_bfloat16* __restrict__ Y) {
    __shared__ __align__(16) char smem[16384];  // A: [0,8K) B: [8K,16K)
    int tid = threadIdx.x;
    int lane = tid & 63, wv = tid >> 6;
    int wr = wv >> 1, wc = wv & 1;
    int lt = (blockIdx.x & 7) * 128 + (blockIdx.x >> 3);
    int bm = lt >> 3, bn = lt & 7;
    int row0 = bm * 64, col0 = bn * 64;

    const ushort* Ag = (const ushort*)Xb;
    const ushort* Bg = (const ushort*)Wkb;

    int aoff[2][2], boff[2][2];
#pragma unroll
    for (int ks = 0; ks < 2; ++ks) {
        int cb = ks * 4 + (lane >> 4);  // 16B chunk in K
#pragma unroll
        for (int i = 0; i < 2; ++i) {
            int ra = wr * 32 + i * 16 + (lane & 15);
            aoff[i][ks] = ra * 128 + (cb ^ (ra & 7)) * 16;
            int rb = wc * 32 + i * 16 + (lane & 15);
            boff[i][ks] = 8192 + rb * 128 + (cb ^ (rb & 7)) * 16;
        }
    }
    int srow[2], sgb[2];
#pragma unroll
    for (int i = 0; i < 2; ++i) {
        srow[i] = i * 32 + wv * 8 + (lane >> 3);
        sgb[i] = (lane & 7) ^ (srow[i] & 7);
    }

    f32x4 acc[2][2] = {};
    for (int k0 = 0; k0 < F; k0 += 64) {
        __syncthreads();
#pragma unroll
        for (int i = 0; i < 2; ++i) {
            const ushort* ga = Ag + (size_t)(row0 + srow[i]) * F + k0 + sgb[i] * 8;
            __builtin_amdgcn_global_load_lds(
                (const __attribute__((address_space(1))) uint32_t*)ga,
                (__attribute__((address_space(3))) uint32_t*)(smem + wv * 1024 + i * 4096),
                16, 0, 0);
            const ushort* gb = Bg + (size_t)(col0 + srow[i]) * F + k0 + sgb[i] * 8;
            __builtin_amdgcn_global_load_lds(
                (const __attribute__((address_space(1))) uint32_t*)gb,
                (__attribute__((address_space(3))) uint32_t*)(smem + 8192 + wv * 1024 + i * 4096),
                16, 0, 0);
        }
        __syncthreads();
#pragma unroll
        for (int ks = 0; ks < 2; ++ks) {
            short8 af[2], bf[2];
#pragma unroll
            for (int i = 0; i < 2; ++i) {
                af[i] = *reinterpret_cast<short8*>(smem + aoff[i][ks]);
                bf[i] = *reinterpret_cast<short8*>(smem + boff[i][ks]);
            }
#pragma unroll
            for (int mi = 0; mi < 2; ++mi)
#pragma unroll
                for (int ni = 0; ni < 2; ++ni)
                    acc[mi][ni] = __builtin_amdgcn_mfma_f32_16x16x32_bf16(
                        af[mi], bf[ni], acc[mi][ni], 0, 0, 0);
        }
    }
    int cr = (lane >> 4) * 4, cc = lane & 15;
#pragma unroll
    for (int mi = 0; mi < 2; ++mi)
#pragma unroll
        for (int ni = 0; ni < 2; ++ni) {
            int gr = row0 + wr * 32 + mi * 16 + cr;
            int gc = col0 + wc * 32 + ni * 16 + cc;
#pragma unroll
            for (int r = 0; r < 4; ++r)
                Y[(size_t)(gr + r) * HD + gc] =
                    __float2bfloat16(acc[mi][ni][r]);
        }
}

// ---------------- kernel 4: sparse masked softmax + gather + bias + ELU ----
// one block per (b,i), batch->XCD affinity; one wave per head.
// Gather: 16 lanes per neighbor row, 4 neighbors/step, dwordx4 loads;
// weights+idx from one LDS int2; online softmax at 256-chunk granularity.
extern "C" __global__ __launch_bounds__(256) void k_attn_agg(
    const float* __restrict__ A, const float* __restrict__ att,
    const ushort* __restrict__ Y, const float* __restrict__ bias,
    float* __restrict__ out) {
    int g = blockIdx.x;
    int bi = ((g & 7) << 10) | (g >> 3);  // batch (g&7) -> XCD (g&7)
    int b = bi >> 10;
    int tid = threadIdx.x;
    int lane = tid & 63, wv = tid >> 6;
    __shared__ int idxs[N];
    __shared__ int2 ent[H][256];  // (idx, score/weight bits) per head
    __shared__ int wsum[4];

    // Phase A: compact A-row to index list (wave shuffle scan, 2 barriers)
    const float* Arow = A + (size_t)bi * N;
    float4 av = *reinterpret_cast<const float4*>(Arow + tid * 4);
    int cnt = (av.x != 0.f) + (av.y != 0.f) + (av.z != 0.f) + (av.w != 0.f);
    int isc = cnt;
#pragma unroll
    for (int off = 1; off < 64; off <<= 1) {
        int t = __shfl_up(isc, off);
        if (lane >= off) isc += t;
    }
    if (lane == 63) wsum[wv] = isc;
    __syncthreads();
    int prefix = 0;
#pragma unroll
    for (int wj = 0; wj < 4; ++wj) prefix += (wj < wv) ? wsum[wj] : 0;
    int nnz = wsum[0] + wsum[1] + wsum[2] + wsum[3];
    int wo = prefix + isc - cnt;
    int jb = tid * 4;
    if (av.x != 0.f) idxs[wo++] = jb;
    if (av.y != 0.f) idxs[wo++] = jb + 1;
    if (av.z != 0.f) idxs[wo++] = jb + 2;
    if (av.w != 0.f) idxs[wo++] = jb + 3;
    __syncthreads();

    // Phase B: wave wv handles head h = wv. Barrier-free (private ent[h]).
    int h = wv;
    int grp = lane >> 4, sub = lane & 15;
    float sself = att[(size_t)h * ROWS + bi];
    const float* nrow = att + (size_t)(H + h) * ROWS + (size_t)b * N;
    const ushort* Ybase = Y + ((size_t)b * N) * HD + h * D + sub * 8;

    float m = -1e30f, l = 0.f;
    float acc[8] = {};
    for (int c0 = 0; c0 < nnz; c0 += 256) {
        int cn = min(256, nnz - c0);
        // pass 1: scores -> ent[h][k], chunk max
        float lm = -1e30f;
        for (int k = lane; k < cn; k += 64) {
            int idx = idxs[c0 + k];
            float s = sself + nrow[idx];
            s = s >= 0.f ? s : LEAKY * s;
            ent[h][k] = make_int2(idx, __float_as_int(s));
            lm = fmaxf(lm, s);
        }
#pragma unroll
        for (int off = 32; off > 0; off >>= 1)
            lm = fmaxf(lm, __shfl_xor(lm, off));
        float mn = fmaxf(m, lm);
        float scale = __expf(m - mn);
        // pass 2: exp in place, chunk sum
        float ls = 0.f;
        for (int k = lane; k < cn; k += 64) {
            int2 p = ent[h][k];
            float e = __expf(__int_as_float(p.y) - mn);
            ent[h][k].y = __float_as_int(e);
            ls += e;
        }
#pragma unroll
        for (int off = 32; off > 0; off >>= 1) ls += __shfl_xor(ls, off);
        l = fmaf(l, scale, ls);
#pragma unroll
        for (int q = 0; q < 8; ++q) acc[q] *= scale;
        m = mn;
        // pass 3: gather, 4 neighbors/step (16 lanes each), unroll 2
        for (int k = 0; k < cn; k += 8) {
            int kk0 = k + grp, kk1 = k + 4 + grp;
            float w0 = 0.f, w1 = 0.f;
            int i0 = 0, i1 = 0;
            if (kk0 < cn) {
                int2 p = ent[h][kk0];
                i0 = p.x; w0 = __int_as_float(p.y);
            }
            if (kk1 < cn) {
                int2 p = ent[h][kk1];
                i1 = p.x; w1 = __int_as_float(p.y);
            }
            uint4 y0 = *reinterpret_cast<const uint4*>(Ybase + ((size_t)i0 * HD));
            uint4 y1 = *reinterpret_cast<const uint4*>(Ybase + ((size_t)i1 * HD));
            acc[0] = fmaf(w0, blo(y0.x), acc[0]);
            acc[1] = fmaf(w0, bhi(y0.x), acc[1]);
            acc[2] = fmaf(w0, blo(y0.y), acc[2]);
            acc[3] = fmaf(w0, bhi(y0.y), acc[3]);
            acc[4] = fmaf(w0, blo(y0.z), acc[4]);
            acc[5] = fmaf(w0, bhi(y0.z), acc[5]);
            acc[6] = fmaf(w0, blo(y0.w), acc[6]);
            acc[7] = fmaf(w0, bhi(y0.w), acc[7]);
            acc[0] = fmaf(w1, blo(y1.x), acc[0]);
            acc[1] = fmaf(w1, bhi(y1.x), acc[1]);
            acc[2] = fmaf(w1, blo(y1.y), acc[2]);
            acc[3] = fmaf(w1, bhi(y1.y), acc[3]);
            acc[4] = fmaf(w1, blo(y1.z), acc[4]);
            acc[5] = fmaf(w1, bhi(y1.z), acc[5]);
            acc[6] = fmaf(w1, blo(y1.w), acc[6]);
            acc[7] = fmaf(w1, bhi(y1.w), acc[7]);
        }
    }
    // cross-group reduction (grp 0..3 hold disjoint neighbor subsets)
#pragma unroll
    for (int q = 0; q < 8; ++q) {
        acc[q] += __shfl_xor(acc[q], 16);
        acc[q] += __shfl_xor(acc[q], 32);
    }
    if (grp == 0) {
        float inv = 1.f / l;
        int cbase = h * D + sub * 8;
        float4 b0 = *reinterpret_cast<const float4*>(bias + cbase);
        float4 b1 = *reinterpret_cast<const float4*>(bias + cbase + 4);
        float o[8];
        o[0] = acc[0] * inv + b0.x; o[1] = acc[1] * inv + b0.y;
        o[2] = acc[2] * inv + b0.z; o[3] = acc[3] * inv + b0.w;
        o[4] = acc[4] * inv + b1.x; o[5] = acc[5] * inv + b1.y;
        o[6] = acc[6] * inv + b1.z; o[7] = acc[7] * inv + b1.w;
#pragma unroll
        for (int q = 0; q < 8; ++q) o[q] = o[q] > 0.f ? o[q] : expm1f(o[q]);
        float* op = out + (size_t)bi * HD + cbase;
        *reinterpret_cast<float4*>(op) = make_float4(o[0], o[1], o[2], o[3]);
        *reinterpret_cast<float4*>(op + 4) = make_float4(o[4], o[5], o[6], o[7]);
    }
}

extern "C" void kernel_launch(void* const* d_in, const int* in_sizes, int n_in,
                              void* d_out, int out_size, void* d_ws,
                              size_t ws_size, hipStream_t stream) {
    const float* X    = (const float*)d_in[0];
    const float* A    = (const float*)d_in[1];
    const float* Watt = (const float*)d_in[2];
    const float* aatt = (const float*)d_in[3];
    const float* Wk   = (const float*)d_in[4];
    const float* bias = (const float*)d_in[5];
    float* out = (float*)d_out;
    float* ws  = (float*)d_ws;

    float* uv  = ws + UV_OFF;
    float* att = ws + ATT_OFF;
    __hip_bfloat16* Yb  = (__hip_bfloat16*)(ws + Y_OFF);
    __hip_bfloat16* Xb  = (__hip_bfloat16*)(ws + XB_OFF);
    __hip_bfloat16* Wkb = (__hip_bfloat16*)(ws + WKB_OFF);

    hipLaunchKernelGGL(k_pre, dim3(32), dim3(256), 0, stream, Watt, aatt, Wk,
                       uv, Wkb);
    hipLaunchKernelGGL(k_att, dim3(ROWS / 4), dim3(256), 0, stream, X, uv, att, Xb);
    hipLaunchKernelGGL(k_gemm, dim3((ROWS / 64) * (HD / 64)), dim3(256), 0,
                       stream, Xb, Wkb, Yb);
    hipLaunchKernelGGL(k_attn_agg, dim3(ROWS), dim3(256), 0, stream, A, att,
                       (const ushort*)Yb, bias, out);
}